// Round 2
// baseline (218.563 us; speedup 1.0000x reference)
//
#include <hip/hip_runtime.h>

// Reference collapses: softmax over a size-1 key axis == 1.0, so
// out[bn,t,:] = padded[bn,t,:] + (masked_mean_t(padded[bn]) @ Wv + bv).
// q/k/rope/positions/sum_token are dead code.
//
// R6: 2-kernel split, replacing R5's single fused kernel (75us, 2.2 TB/s,
// phase-serialization-bound: load->barrier->reduce->matvec->store in
// lockstep at 2 blocks/CU left HBM idle during reduce/matvec and L2 idle
// during load/store).
//   K1: per-bn masked colsum (streaming, no register residency) + matvec
//       -> v[bn].  One block owns one bn: no cross-block dep, no atomics.
//       Reads padded 100 MB (half L3-hit per R5's FETCH), writes 786 KB.
//   K2: out = padded + v[col].  Pure stream; padded re-read is L3-warm
//       (just touched by K1).  100 MB read + 106 MB write.
// Two short phase-homogeneous kernels saturate better than one lockstep
// fused kernel: predicted K1 ~25us + K2 ~30us vs 75us fused.

#define DM 384
#define TT 128
#define C4 96          // DM / 4
#define BN_TOT 512
#define NR1 8          // K1 row-groups (768 = 8 * 96)

// ---------------- K1: masked colsum + matvec -> v ----------------
__global__ __launch_bounds__(768) void k1_colsum_matvec(
    const float* __restrict__ padded,
    const int*   __restrict__ masks,
    const float* __restrict__ Wv,
    const float* __restrict__ bv,
    float*       __restrict__ ws_v)      // (BN_TOT, DM)
{
    const int bn = blockIdx.x;
    const int t  = threadIdx.x;
    const int c  = t % C4;        // float4 column 0..95
    const int r  = t / C4;        // row-group 0..7

    __shared__ float  w_sh[TT];
    __shared__ float4 part_sh[NR1][C4];   // 6 KB
    __shared__ float  summ[DM];

    if (t < TT) w_sh[t] = (float)masks[bn * TT + t];
    __syncthreads();

    // ---- streaming masked column sums: 16 rows/thread, 2 accumulators ----
    const float4* __restrict__ p4 =
        (const float4*)padded + (size_t)bn * TT * C4;
    float4 acc0 = make_float4(0.f, 0.f, 0.f, 0.f);
    float4 acc1 = make_float4(0.f, 0.f, 0.f, 0.f);
    #pragma unroll
    for (int i = 0; i < 8; ++i) {
        const int   rowA = r + (2 * i)     * NR1;
        const int   rowB = r + (2 * i + 1) * NR1;
        const float wA = w_sh[rowA];
        const float wB = w_sh[rowB];
        const float4 xA = p4[rowA * C4 + c];
        const float4 xB = p4[rowB * C4 + c];
        acc0.x += xA.x * wA; acc0.y += xA.y * wA;
        acc0.z += xA.z * wA; acc0.w += xA.w * wA;
        acc1.x += xB.x * wB; acc1.y += xB.y * wB;
        acc1.z += xB.z * wB; acc1.w += xB.w * wB;
    }
    acc0.x += acc1.x; acc0.y += acc1.y; acc0.z += acc1.z; acc0.w += acc1.w;
    part_sh[r][c] = acc0;
    __syncthreads();

    // ---- finalize summary (96 threads; denom via 4 parallel chains) ----
    if (t < C4) {
        float d0 = 0.f, d1 = 0.f, d2 = 0.f, d3 = 0.f;
        #pragma unroll
        for (int i = 0; i < 32; ++i) {
            d0 += w_sh[i];      d1 += w_sh[32 + i];
            d2 += w_sh[64 + i]; d3 += w_sh[96 + i];
        }
        const float inv = 1.0f / fmaxf((d0 + d1) + (d2 + d3), 1e-6f);

        float4 s = part_sh[0][t];
        #pragma unroll
        for (int g = 1; g < NR1; ++g) {
            const float4 p = part_sh[g][t];
            s.x += p.x; s.y += p.y; s.z += p.z; s.w += p.w;
        }
        s.x *= inv; s.y *= inv; s.z *= inv; s.w *= inv;
        ((float4*)summ)[t] = s;
    }
    __syncthreads();

    // ---- matvec v = summary @ Wv + bv; block reads Wv exactly once ----
    float4 a = make_float4(0.f, 0.f, 0.f, 0.f);
    const float4* __restrict__ wv4 = (const float4*)Wv;
    const int e0 = r * (DM / NR1);       // 48 rows per row-group
    #pragma unroll 8
    for (int i = 0; i < DM / NR1; ++i) {
        const int   e = e0 + i;
        const float s = summ[e];                  // LDS broadcast
        const float4 w = wv4[(size_t)e * C4 + c]; // coalesced, L2-hot
        a.x += s * w.x; a.y += s * w.y; a.z += s * w.z; a.w += s * w.w;
    }
    part_sh[r][c] = a;
    __syncthreads();

    if (t < C4) {
        float4 v = ((const float4*)bv)[t];
        #pragma unroll
        for (int g = 0; g < NR1; ++g) {
            const float4 p = part_sh[g][t];
            v.x += p.x; v.y += p.y; v.z += p.z; v.w += p.w;
        }
        ((float4*)(ws_v + (size_t)bn * DM))[t] = v;
    }
}

// ---------------- K2: out = padded + v ----------------
// block b: bn = b>>2, quarter q = b&3 (rows q*32 .. q*32+31). 384 threads.
__global__ __launch_bounds__(384) void k2_add(
    const float* __restrict__ padded,
    const float* __restrict__ ws_v,
    float*       __restrict__ out)
{
    const int bn = blockIdx.x >> 2;
    const int q  = blockIdx.x & 3;
    const int t  = threadIdx.x;
    const int c  = t % C4;
    const int r  = t / C4;            // 0..3

    __shared__ float4 v_sh[C4];
    if (t < C4) v_sh[t] = ((const float4*)(ws_v + (size_t)bn * DM))[t];
    __syncthreads();

    const size_t base = (size_t)bn * TT * C4 + (size_t)q * 32 * C4;
    const float4* __restrict__ p4 = (const float4*)padded + base;
    float4*       __restrict__ o4 = (float4*)out + base;

    const float4 v = v_sh[c];
    #pragma unroll
    for (int i = 0; i < 8; ++i) {
        const int tt = r + i * 4;     // 0..31 within quarter
        float4 x = p4[tt * C4 + c];
        x.x += v.x; x.y += v.y; x.z += v.z; x.w += v.w;
        o4[tt * C4 + c] = x;
    }
}

extern "C" void kernel_launch(void* const* d_in, const int* in_sizes, int n_in,
                              void* d_out, int out_size, void* d_ws, size_t ws_size,
                              hipStream_t stream) {
    const float* padded = (const float*)d_in[0];
    // d_in[1] sum_token, d_in[2] positions_3d, d_in[3..6] Wq/bq/Wk/bk: dead
    const float* Wv     = (const float*)d_in[7];
    const float* bv     = (const float*)d_in[8];
    const int*   masks  = (const int*)d_in[9];
    float* out = (float*)d_out;

    float* ws_v = (float*)d_ws;       // 512*384 floats = 786 KB

    k1_colsum_matvec<<<BN_TOT, 768, 0, stream>>>(padded, masks, Wv, bv, ws_v);
    k2_add<<<BN_TOT * 4, 384, 0, stream>>>(padded, ws_v, out);
}